// Round 1
// baseline (712.262 us; speedup 1.0000x reference)
//
#include <hip/hip_runtime.h>
#include <math.h>

#define NN 50000
#define NE 800000
#define INF_ 128
#define HEADS 4
#define OUTF 16
#define HC 64          // HEADS*OUTF
#define NEG_SLOPE 0.2f

// ---------- helpers ----------
__device__ __forceinline__ unsigned fmap(float f) {
    unsigned b = __float_as_uint(f);
    return b ^ ((unsigned)((int)b >> 31) | 0x80000000u);
}
__device__ __forceinline__ float funmap(unsigned u) {
    unsigned b = (u & 0x80000000u) ? (u ^ 0x80000000u) : ~u;
    return __uint_as_float(b);
}

// ---------- K0: zero a region ----------
__global__ void k_zero(float* __restrict__ p, size_t n) {
    size_t i = (size_t)blockIdx.x * blockDim.x + threadIdx.x;
    size_t stride = (size_t)gridDim.x * blockDim.x;
    for (; i < n; i += stride) p[i] = 0.f;
}

// ---------- K1: degree + edge_attr sum per dst ----------
__global__ void k_deg(const int* __restrict__ ei, const float* __restrict__ ea,
                      float* __restrict__ deg, float* __restrict__ easum) {
    int e = blockIdx.x * 256 + threadIdx.x;
    if (e >= NE) return;
    int dst = ei[NE + e];
    atomicAdd(&deg[dst], 1.f);
    atomicAdd(&easum[dst], ea[e]);
}

// ---------- K2: ea_mean = easum / max(deg,1) (in place) ----------
__global__ void k_mean(const float* __restrict__ deg, float* __restrict__ easum) {
    int n = blockIdx.x * 256 + threadIdx.x;
    if (n < NN) easum[n] = easum[n] / fmaxf(deg[n], 1.f);
}

// ---------- K3: xw = x @ W, plus a_src/a_dst logits ----------
__global__ __launch_bounds__(256) void k_xw(
    const float* __restrict__ x, const float* __restrict__ W,
    const float* __restrict__ att_src, const float* __restrict__ att_dst,
    float* __restrict__ xw, float* __restrict__ a_src, float* __restrict__ a_dst) {
    __shared__ float sW[INF_ * HC];   // 32 KB
    __shared__ float sx[4][INF_];     // 2 KB
    int t = threadIdx.x;
    for (int i = t; i < INF_ * HC; i += 256) sW[i] = W[i];
    int n0 = blockIdx.x * 4;
    for (int i = t; i < 4 * INF_; i += 256) {
        int r = i >> 7, c = i & 127;
        int n = n0 + r;
        sx[r][c] = (n < NN) ? x[(size_t)n * INF_ + c] : 0.f;
    }
    __syncthreads();
    int nl = t >> 6;        // node within block
    int c  = t & 63;        // output column
    float acc = 0.f;
#pragma unroll
    for (int k = 0; k < INF_; ++k) acc = fmaf(sx[nl][k], sW[k * HC + c], acc);
    int n = n0 + nl;
    if (n < NN) {
        xw[(size_t)n * HC + c] = acc;
        int h = c >> 4, cc = c & 15;
        float ps = acc * att_src[h * OUTF + cc];
        float pd = acc * att_dst[h * OUTF + cc];
#pragma unroll
        for (int m = 1; m < 16; m <<= 1) {
            ps += __shfl_xor(ps, m);
            pd += __shfl_xor(pd, m);
        }
        if (cc == 0) { a_src[n * HEADS + h] = ps; a_dst[n * HEADS + h] = pd; }
    }
}

// ---------- K4: alpha logits + segment max ----------
__global__ void k_alpha(const int* __restrict__ ei, const float* __restrict__ ea,
                        const float* __restrict__ ea_mean,
                        const float* __restrict__ a_src, const float* __restrict__ a_dst,
                        const float* __restrict__ W_edge, const float* __restrict__ att_edge,
                        float* __restrict__ alpha, unsigned* __restrict__ amax) {
    __shared__ float ce[HEADS];
    if (threadIdx.x < HEADS) {
        float s = 0.f;
        for (int c = 0; c < OUTF; ++c)
            s += W_edge[threadIdx.x * OUTF + c] * att_edge[threadIdx.x * OUTF + c];
        ce[threadIdx.x] = s;
    }
    __syncthreads();
    int e = blockIdx.x * 256 + threadIdx.x;
    if (e >= NE + NN) return;
    int src, dst; float eav;
    if (e < NE) { src = ei[e]; dst = ei[NE + e]; eav = ea[e]; }
    else        { src = dst = e - NE; eav = ea_mean[src]; }
    float4 as = *(const float4*)&a_src[src * HEADS];
    float4 ad = *(const float4*)&a_dst[dst * HEADS];
    float v[4] = { as.x + ad.x + eav * ce[0],
                   as.y + ad.y + eav * ce[1],
                   as.z + ad.z + eav * ce[2],
                   as.w + ad.w + eav * ce[3] };
    float4 out;
    float* po = &out.x;
#pragma unroll
    for (int h = 0; h < HEADS; ++h) {
        float a = v[h] > 0.f ? v[h] : NEG_SLOPE * v[h];
        po[h] = a;
        atomicMax(&amax[dst * HEADS + h], fmap(a));
    }
    *(float4*)&alpha[(size_t)e * HEADS] = out;
}

// ---------- K5: ex = exp(alpha - amax[dst]); denom += ex ----------
__global__ void k_ex(const int* __restrict__ ei, const unsigned* __restrict__ amax,
                     float* __restrict__ alpha, float* __restrict__ denom) {
    int e = blockIdx.x * 256 + threadIdx.x;
    if (e >= NE + NN) return;
    int dst = (e < NE) ? ei[NE + e] : (e - NE);
    float4 a = *(const float4*)&alpha[(size_t)e * HEADS];
    uint4 mu = *(const uint4*)&amax[dst * HEADS];
    float4 ex;
    ex.x = expf(a.x - funmap(mu.x));
    ex.y = expf(a.y - funmap(mu.y));
    ex.z = expf(a.z - funmap(mu.z));
    ex.w = expf(a.w - funmap(mu.w));
    *(float4*)&alpha[(size_t)e * HEADS] = ex;
    atomicAdd(&denom[dst * HEADS + 0], ex.x);
    atomicAdd(&denom[dst * HEADS + 1], ex.y);
    atomicAdd(&denom[dst * HEADS + 2], ex.z);
    atomicAdd(&denom[dst * HEADS + 3], ex.w);
}

// ---------- K6: scatter messages ----------
__global__ void k_scatter(const int* __restrict__ ei, const float* __restrict__ xw,
                          const float* __restrict__ exb, const float* __restrict__ denom,
                          float* __restrict__ acc) {
    size_t t = (size_t)blockIdx.x * 256 + threadIdx.x;
    size_t e = t >> 6;
    int c = (int)(t & 63);
    if (e >= (size_t)(NE + NN)) return;
    int src, dst;
    if (e < NE) { src = ei[e]; dst = ei[NE + e]; }
    else        { src = dst = (int)(e - NE); }
    int h = c >> 4;
    float att = exb[e * HEADS + h] / denom[dst * HEADS + h];
    float v = xw[(size_t)src * HC + c] * att;
    atomicAdd(&acc[(size_t)dst * HC + c], v);
}

// ---------- K7: bias + relu ----------
__global__ void k_out(const float* __restrict__ acc, const float* __restrict__ bias,
                      float* __restrict__ out) {
    size_t i = (size_t)blockIdx.x * 256 + threadIdx.x;
    if (i >= (size_t)NN * HC) return;
    int c = (int)(i & 63);
    out[i] = fmaxf(acc[i] + bias[c], 0.f);
}

extern "C" void kernel_launch(void* const* d_in, const int* in_sizes, int n_in,
                              void* d_out, int out_size, void* d_ws, size_t ws_size,
                              hipStream_t stream) {
    const float* x        = (const float*)d_in[0];
    const int*   ei       = (const int*)d_in[1];
    const float* ea       = (const float*)d_in[2];
    const float* W        = (const float*)d_in[3];
    const float* W_edge   = (const float*)d_in[4];
    const float* att_src  = (const float*)d_in[5];
    const float* att_dst  = (const float*)d_in[6];
    const float* att_edge = (const float*)d_in[7];
    const float* bias     = (const float*)d_in[8];
    float* out = (float*)d_out;

    // workspace layout (floats)
    float* ws = (float*)d_ws;
    float*    xw      = ws;                                  // 64N
    float*    a_src   = xw + (size_t)64 * NN;                // 4N
    float*    a_dst   = a_src + (size_t)4 * NN;              // 4N
    float*    alpha   = a_dst + (size_t)4 * NN;              // 4(E+N)
    float*    zbase   = alpha + (size_t)4 * (NE + NN);       // zeroed region:
    float*    deg     = zbase;                               // N
    float*    ea_mean = deg + NN;                            // N (sum, then mean)
    unsigned* amax    = (unsigned*)(ea_mean + NN);           // 4N
    float*    denom   = (float*)(amax + (size_t)4 * NN);     // 4N
    float*    acc     = denom + (size_t)4 * NN;              // 64N
    size_t zcount = (size_t)NN * (1 + 1 + 4 + 4 + 64);

    k_zero<<<2048, 256, 0, stream>>>(zbase, zcount);
    k_deg<<<(NE + 255) / 256, 256, 0, stream>>>(ei, ea, deg, ea_mean);
    k_xw<<<(NN + 3) / 4, 256, 0, stream>>>(x, W, att_src, att_dst, xw, a_src, a_dst);
    k_mean<<<(NN + 255) / 256, 256, 0, stream>>>(deg, ea_mean);
    int ET = NE + NN;
    k_alpha<<<(ET + 255) / 256, 256, 0, stream>>>(ei, ea, ea_mean, a_src, a_dst,
                                                  W_edge, att_edge, alpha, amax);
    k_ex<<<(ET + 255) / 256, 256, 0, stream>>>(ei, amax, alpha, denom);
    k_scatter<<<(int)(((size_t)ET * 64 + 255) / 256), 256, 0, stream>>>(ei, xw, alpha, denom, acc);
    k_out<<<(int)(((size_t)NN * HC + 255) / 256), 256, 0, stream>>>(acc, bias, out);
}

// Round 2
// 322.350 us; speedup vs baseline: 2.2096x; 2.2096x over previous
//
#include <hip/hip_runtime.h>
#include <math.h>

#define NN 50000
#define NE 800000
#define INF_ 128
#define HEADS 4
#define OUTF 16
#define HC 64
#define NEG_SLOPE 0.2f
#define SCAN_NB 196   // ceil(50000/256)

// ---------- K0: zero ints/floats ----------
__global__ void k_zero(int* __restrict__ p, size_t n) {
    size_t i = (size_t)blockIdx.x * blockDim.x + threadIdx.x;
    size_t stride = (size_t)gridDim.x * blockDim.x;
    for (; i < n; i += stride) p[i] = 0;
}

// ---------- K1: degree + edge_attr sum per dst ----------
__global__ void k_deg(const int* __restrict__ ei, const float* __restrict__ ea,
                      int* __restrict__ deg, float* __restrict__ easum) {
    int e = blockIdx.x * 256 + threadIdx.x;
    if (e >= NE) return;
    int dst = ei[NE + e];
    atomicAdd(&deg[dst], 1);
    atomicAdd(&easum[dst], ea[e]);
}

// ---------- K2: xw = x @ W + per-node logits ----------
// 64 nodes/block, 256 threads, 16 outputs/thread (4 nodes x 4 cols)
__global__ __launch_bounds__(256) void k_xw(
    const float* __restrict__ x, const float* __restrict__ W,
    const float* __restrict__ att_src, const float* __restrict__ att_dst,
    float* __restrict__ xw, float* __restrict__ a_src, float* __restrict__ a_dst) {
    __shared__ float sW[INF_ * HC];       // 32 KB, k-major [128][64]
    __shared__ float sx[64 * 132];        // 33.8 KB, padded rows
    int t = threadIdx.x;
    int n0 = blockIdx.x * 64;
    // load W (2048 float4)
    for (int i = t; i < (INF_ * HC) / 4; i += 256)
        ((float4*)sW)[i] = ((const float4*)W)[i];
    // load x tile (64 x 128), padded row stride 132
    for (int i = t; i < 64 * 32; i += 256) {
        int r = i >> 5, k4 = (i & 31) * 4;
        int n = n0 + r;
        float4 v = (n < NN) ? *(const float4*)&x[(size_t)n * INF_ + k4]
                            : make_float4(0.f, 0.f, 0.f, 0.f);
        *(float4*)&sx[r * 132 + k4] = v;
    }
    __syncthreads();
    int cg = t & 15;          // col group -> c0 = cg*4
    int q  = t >> 4;          // node quad  -> nodes q*4 .. q*4+3
    int c0 = cg * 4;
    float acc[4][4];
#pragma unroll
    for (int j = 0; j < 4; ++j)
#pragma unroll
        for (int i = 0; i < 4; ++i) acc[j][i] = 0.f;
#pragma unroll 4
    for (int k = 0; k < INF_; ++k) {
        float4 w = *(const float4*)&sW[k * HC + c0];
#pragma unroll
        for (int j = 0; j < 4; ++j) {
            float xv = sx[(q * 4 + j) * 132 + k];
            acc[j][0] = fmaf(xv, w.x, acc[j][0]);
            acc[j][1] = fmaf(xv, w.y, acc[j][1]);
            acc[j][2] = fmaf(xv, w.z, acc[j][2]);
            acc[j][3] = fmaf(xv, w.w, acc[j][3]);
        }
    }
    int h = c0 >> 4;
    int cl = c0 & 15;
    float ps[4], pd[4];
#pragma unroll
    for (int j = 0; j < 4; ++j) {
        float s_ = 0.f, d_ = 0.f;
#pragma unroll
        for (int i = 0; i < 4; ++i) {
            s_ = fmaf(acc[j][i], att_src[h * OUTF + cl + i], s_);
            d_ = fmaf(acc[j][i], att_dst[h * OUTF + cl + i], d_);
        }
        ps[j] = s_; pd[j] = d_;
    }
#pragma unroll
    for (int m = 1; m < 4; m <<= 1)
#pragma unroll
        for (int j = 0; j < 4; ++j) {
            ps[j] += __shfl_xor(ps[j], m);
            pd[j] += __shfl_xor(pd[j], m);
        }
#pragma unroll
    for (int j = 0; j < 4; ++j) {
        int n = n0 + q * 4 + j;
        if (n < NN) {
            *(float4*)&xw[(size_t)n * HC + c0] =
                make_float4(acc[j][0], acc[j][1], acc[j][2], acc[j][3]);
            if ((cg & 3) == 0) {
                a_src[n * HEADS + h] = ps[j];
                a_dst[n * HEADS + h] = pd[j];
            }
        }
    }
}

// ---------- scan (3 kernels) ----------
__global__ void k_scan1(const int* __restrict__ deg, int* __restrict__ offs,
                        int* __restrict__ bsum) {
    __shared__ int sd[256];
    int t = threadIdx.x;
    int i = blockIdx.x * 256 + t;
    int v = (i < NN) ? deg[i] : 0;
    sd[t] = v; __syncthreads();
    for (int o = 1; o < 256; o <<= 1) {
        int a = (t >= o) ? sd[t - o] : 0;
        __syncthreads();
        sd[t] += a;
        __syncthreads();
    }
    if (i < NN) offs[i] = sd[t] - v;
    if (t == 255) bsum[blockIdx.x] = sd[255];
}
__global__ void k_scan2(const int* __restrict__ bsum, int* __restrict__ boff) {
    __shared__ int sd[256];
    int t = threadIdx.x;
    int v = (t < SCAN_NB) ? bsum[t] : 0;
    sd[t] = v; __syncthreads();
    for (int o = 1; o < 256; o <<= 1) {
        int a = (t >= o) ? sd[t - o] : 0;
        __syncthreads();
        sd[t] += a;
        __syncthreads();
    }
    if (t < SCAN_NB) boff[t] = sd[t] - v;
}
__global__ void k_scan3(const int* __restrict__ boff, int* __restrict__ offs,
                        int* __restrict__ cursor) {
    int i = blockIdx.x * 256 + threadIdx.x;
    if (i < NN) {
        int o = offs[i] + boff[blockIdx.x];
        offs[i] = o;
        cursor[i] = o;
    }
}

// ---------- K3: fill CSR edge list sorted by dst ----------
__global__ void k_fill(const int* __restrict__ ei, const float* __restrict__ ea,
                       int* __restrict__ cursor, uint2* __restrict__ esort) {
    int e = blockIdx.x * 256 + threadIdx.x;
    if (e >= NE) return;
    int dst = ei[NE + e];
    int pos = atomicAdd(&cursor[dst], 1);
    uint2 pk;
    pk.x = (unsigned)ei[e];
    pk.y = __float_as_uint(ea[e]);
    esort[pos] = pk;
}

// ---------- K4: gather — one wave per dst node, lane = channel ----------
__global__ __launch_bounds__(256) void k_gather(
    const uint2* __restrict__ esort, const int* __restrict__ offs,
    const int* __restrict__ deg, const float* __restrict__ easum,
    const float* __restrict__ a_src, const float* __restrict__ a_dst,
    const float* __restrict__ xw,
    const float* __restrict__ W_edge, const float* __restrict__ att_edge,
    const float* __restrict__ bias, float* __restrict__ out) {
    __shared__ float sce[HEADS];
    if (threadIdx.x < HEADS) {
        float s_ = 0.f;
        for (int k = 0; k < OUTF; ++k)
            s_ = fmaf(W_edge[threadIdx.x * OUTF + k], att_edge[threadIdx.x * OUTF + k], s_);
        sce[threadIdx.x] = s_;
    }
    __syncthreads();
    int lane = threadIdx.x & 63;
    int wid = (blockIdx.x * 256 + threadIdx.x) >> 6;
    if (wid >= NN) return;
    int n = wid;
    int c = lane, h = c >> 4;
    float ce = sce[h];
    int start = offs[n];
    int cnt = deg[n];
    float adst = a_dst[n * HEADS + h];
    // self-loop (fill_value='mean' edge_attr)
    float eavm = easum[n] / fmaxf((float)cnt, 1.f);
    float al = a_src[n * HEADS + h] + adst + eavm * ce;
    al = al > 0.f ? al : NEG_SLOPE * al;
    float m = al, s = 1.f;
    float acc = xw[(size_t)n * HC + c];
    // prologue prefetch
    uint2 pk; float asrc = 0.f, xwv = 0.f;
    if (cnt > 0) {
        pk = esort[start];
        asrc = a_src[pk.x * HEADS + h];
        xwv = xw[(size_t)pk.x * HC + c];
    }
    for (int i = 0; i < cnt; ++i) {
        uint2 pk_n = pk; float asrc_n = asrc, xw_n = xwv;
        if (i + 1 < cnt) {
            pk_n = esort[start + i + 1];
            asrc_n = a_src[pk_n.x * HEADS + h];
            xw_n = xw[(size_t)pk_n.x * HC + c];
        }
        float eav = __uint_as_float(pk.y);
        float a2 = asrc + adst + eav * ce;
        a2 = a2 > 0.f ? a2 : NEG_SLOPE * a2;
        float mn = fmaxf(m, a2);
        float r = __expf(m - mn);
        float p = __expf(a2 - mn);
        s = s * r + p;
        acc = acc * r + p * xwv;
        m = mn;
        pk = pk_n; asrc = asrc_n; xwv = xw_n;
    }
    out[(size_t)n * HC + c] = fmaxf(acc / s + bias[c], 0.f);
}

extern "C" void kernel_launch(void* const* d_in, const int* in_sizes, int n_in,
                              void* d_out, int out_size, void* d_ws, size_t ws_size,
                              hipStream_t stream) {
    const float* x        = (const float*)d_in[0];
    const int*   ei       = (const int*)d_in[1];
    const float* ea       = (const float*)d_in[2];
    const float* W        = (const float*)d_in[3];
    const float* W_edge   = (const float*)d_in[4];
    const float* att_src  = (const float*)d_in[5];
    const float* att_dst  = (const float*)d_in[6];
    const float* att_edge = (const float*)d_in[7];
    const float* bias     = (const float*)d_in[8];
    float* out = (float*)d_out;

    // workspace layout
    float* ws = (float*)d_ws;
    float* xw     = ws;                               // 64N floats
    uint2* esort  = (uint2*)(xw + (size_t)HC * NN);   // E uint2 (8B aligned)
    float* a_src  = (float*)(esort + NE);             // 4N
    float* a_dst  = a_src + (size_t)HEADS * NN;       // 4N
    int*   deg    = (int*)(a_dst + (size_t)HEADS * NN); // N
    float* easum  = (float*)(deg + NN);               // N
    int*   offs   = (int*)(easum + NN);               // N
    int*   cursor = offs + NN;                        // N
    int*   bsum   = cursor + NN;                      // 256
    int*   boff   = bsum + 256;                       // 256

    k_zero<<<128, 256, 0, stream>>>(deg, (size_t)2 * NN);   // deg + easum
    k_deg<<<(NE + 255) / 256, 256, 0, stream>>>(ei, ea, deg, easum);
    k_xw<<<(NN + 63) / 64, 256, 0, stream>>>(x, W, att_src, att_dst, xw, a_src, a_dst);
    k_scan1<<<SCAN_NB, 256, 0, stream>>>(deg, offs, bsum);
    k_scan2<<<1, 256, 0, stream>>>(bsum, boff);
    k_scan3<<<SCAN_NB, 256, 0, stream>>>(boff, offs, cursor);
    k_fill<<<(NE + 255) / 256, 256, 0, stream>>>(ei, ea, cursor, esort);
    k_gather<<<(NN * 64 + 255) / 256, 256, 0, stream>>>(
        esort, offs, deg, easum, a_src, a_dst, xw, W_edge, att_edge, bias, out);
}

// Round 3
// 236.159 us; speedup vs baseline: 3.0160x; 1.3650x over previous
//
#include <hip/hip_runtime.h>
#include <math.h>

#define NN 50000
#define NE 800000
#define INF_ 128
#define HEADS 4
#define OUTF 16
#define HC 64
#define NEG_SLOPE 0.2f
#define SCAN_NB 196   // ceil(50000/256)
#define WPB 4         // waves per block

// ---------- K0: zero ----------
__global__ void k_zero(int* __restrict__ p, size_t n) {
    size_t i = (size_t)blockIdx.x * blockDim.x + threadIdx.x;
    size_t stride = (size_t)gridDim.x * blockDim.x;
    for (; i < n; i += stride) p[i] = 0;
}

// ---------- K1: degree per dst ----------
__global__ void k_deg(const int* __restrict__ ei, int* __restrict__ deg) {
    int e = blockIdx.x * 256 + threadIdx.x;
    if (e >= NE) return;
    atomicAdd(&deg[ei[NE + e]], 1);
}

// ---------- K2: xw = x @ W + per-node logits ----------
__global__ __launch_bounds__(256) void k_xw(
    const float* __restrict__ x, const float* __restrict__ W,
    const float* __restrict__ att_src, const float* __restrict__ att_dst,
    float* __restrict__ xw, float* __restrict__ a_src, float* __restrict__ a_dst) {
    __shared__ float sW[INF_ * HC];       // 32 KB, k-major [128][64]
    __shared__ float sx[64 * 132];        // padded rows
    int t = threadIdx.x;
    int n0 = blockIdx.x * 64;
    for (int i = t; i < (INF_ * HC) / 4; i += 256)
        ((float4*)sW)[i] = ((const float4*)W)[i];
    for (int i = t; i < 64 * 32; i += 256) {
        int r = i >> 5, k4 = (i & 31) * 4;
        int n = n0 + r;
        float4 v = (n < NN) ? *(const float4*)&x[(size_t)n * INF_ + k4]
                            : make_float4(0.f, 0.f, 0.f, 0.f);
        *(float4*)&sx[r * 132 + k4] = v;
    }
    __syncthreads();
    int cg = t & 15;
    int q  = t >> 4;
    int c0 = cg * 4;
    float acc[4][4];
#pragma unroll
    for (int j = 0; j < 4; ++j)
#pragma unroll
        for (int i = 0; i < 4; ++i) acc[j][i] = 0.f;
#pragma unroll 4
    for (int k = 0; k < INF_; ++k) {
        float4 w = *(const float4*)&sW[k * HC + c0];
#pragma unroll
        for (int j = 0; j < 4; ++j) {
            float xv = sx[(q * 4 + j) * 132 + k];
            acc[j][0] = fmaf(xv, w.x, acc[j][0]);
            acc[j][1] = fmaf(xv, w.y, acc[j][1]);
            acc[j][2] = fmaf(xv, w.z, acc[j][2]);
            acc[j][3] = fmaf(xv, w.w, acc[j][3]);
        }
    }
    int h = c0 >> 4;
    int cl = c0 & 15;
    float ps[4], pd[4];
#pragma unroll
    for (int j = 0; j < 4; ++j) {
        float s_ = 0.f, d_ = 0.f;
#pragma unroll
        for (int i = 0; i < 4; ++i) {
            s_ = fmaf(acc[j][i], att_src[h * OUTF + cl + i], s_);
            d_ = fmaf(acc[j][i], att_dst[h * OUTF + cl + i], d_);
        }
        ps[j] = s_; pd[j] = d_;
    }
#pragma unroll
    for (int m = 1; m < 4; m <<= 1)
#pragma unroll
        for (int j = 0; j < 4; ++j) {
            ps[j] += __shfl_xor(ps[j], m);
            pd[j] += __shfl_xor(pd[j], m);
        }
#pragma unroll
    for (int j = 0; j < 4; ++j) {
        int n = n0 + q * 4 + j;
        if (n < NN) {
            *(float4*)&xw[(size_t)n * HC + c0] =
                make_float4(acc[j][0], acc[j][1], acc[j][2], acc[j][3]);
            if ((cg & 3) == 0) {
                a_src[n * HEADS + h] = ps[j];
                a_dst[n * HEADS + h] = pd[j];
            }
        }
    }
}

// ---------- scan (3 kernels) ----------
__global__ void k_scan1(const int* __restrict__ deg, int* __restrict__ offs,
                        int* __restrict__ bsum) {
    __shared__ int sd[256];
    int t = threadIdx.x;
    int i = blockIdx.x * 256 + t;
    int v = (i < NN) ? deg[i] : 0;
    sd[t] = v; __syncthreads();
    for (int o = 1; o < 256; o <<= 1) {
        int a = (t >= o) ? sd[t - o] : 0;
        __syncthreads();
        sd[t] += a;
        __syncthreads();
    }
    if (i < NN) offs[i] = sd[t] - v;
    if (t == 255) bsum[blockIdx.x] = sd[255];
}
__global__ void k_scan2(const int* __restrict__ bsum, int* __restrict__ boff) {
    __shared__ int sd[256];
    int t = threadIdx.x;
    int v = (t < SCAN_NB) ? bsum[t] : 0;
    sd[t] = v; __syncthreads();
    for (int o = 1; o < 256; o <<= 1) {
        int a = (t >= o) ? sd[t - o] : 0;
        __syncthreads();
        sd[t] += a;
        __syncthreads();
    }
    if (t < SCAN_NB) boff[t] = sd[t] - v;
}
__global__ void k_scan3(const int* __restrict__ boff, int* __restrict__ offs,
                        int* __restrict__ cursor) {
    int i = blockIdx.x * 256 + threadIdx.x;
    if (i < NN) {
        int o = offs[i] + boff[blockIdx.x];
        offs[i] = o;
        cursor[i] = o;
    }
}

// ---------- K3: fill CSR edge list sorted by dst ----------
__global__ void k_fill(const int* __restrict__ ei, const float* __restrict__ ea,
                       int* __restrict__ cursor, uint2* __restrict__ esort) {
    int e = blockIdx.x * 256 + threadIdx.x;
    if (e >= NE) return;
    int dst = ei[NE + e];
    int pos = atomicAdd(&cursor[dst], 1);
    uint2 pk;
    pk.x = (unsigned)ei[e];
    pk.y = __float_as_uint(ea[e]);
    esort[pos] = pk;
}

// ---------- helpers ----------
__device__ __forceinline__ float sel4s(float a, float b, float c, float d, int h) {
    float ab = (h & 1) ? b : a;
    float cd = (h & 1) ? d : c;
    return (h & 2) ? cd : ab;
}
__device__ __forceinline__ float lrelu(float v) {
    return v > 0.f ? v : NEG_SLOPE * v;
}

// ---------- K4: gather, chunked flash-style ----------
__global__ __launch_bounds__(256) void k_gather(
    const uint2* __restrict__ esort, const int* __restrict__ offs,
    const int* __restrict__ deg,
    const float* __restrict__ a_src, const float* __restrict__ a_dst,
    const float* __restrict__ xw,
    const float* __restrict__ W_edge, const float* __restrict__ att_edge,
    const float* __restrict__ bias, float* __restrict__ out) {
    __shared__ __align__(16) float sce[4];
    __shared__ __align__(16) float ldsP[WPB][64][4];
    __shared__ int ldsS[WPB][64];
    int t = threadIdx.x;
    if (t < 4) {
        float s_ = 0.f;
        for (int k = 0; k < OUTF; ++k)
            s_ = fmaf(W_edge[t * OUTF + k], att_edge[t * OUTF + k], s_);
        sce[t] = s_;
    }
    __syncthreads();
    int lane = t & 63;
    int wslot = t >> 6;
    int n = (blockIdx.x << 2) + wslot;   // grid = 12500 blocks exactly
    int hc = lane >> 4;

    float4 ce4 = *(float4*)sce;
    float4 ad4 = *(const float4*)&a_dst[(size_t)n * 4];
    int start = offs[n];
    int cnt = deg[n];

    float m0 = -3e38f, m1 = -3e38f, m2 = -3e38f, m3 = -3e38f;
    float s = 0.f, acc = 0.f, easum = 0.f;

    int nch = (cnt + 63) >> 6;
    for (int ch = 0; ch < nch; ++ch) {
        int base = start + (ch << 6);
        int cc = cnt - (ch << 6); if (cc > 64) cc = 64;
        bool valid = lane < cc;
        float l0, l1, l2, l3, eav = 0.f; int srci = 0;
        if (valid) {
            uint2 pk = esort[base + lane];
            srci = (int)pk.x;
            eav = __uint_as_float(pk.y);
            float4 as4 = *(const float4*)&a_src[(size_t)srci * 4];
            l0 = lrelu(as4.x + ad4.x + eav * ce4.x);
            l1 = lrelu(as4.y + ad4.y + eav * ce4.y);
            l2 = lrelu(as4.z + ad4.z + eav * ce4.z);
            l3 = lrelu(as4.w + ad4.w + eav * ce4.w);
        } else {
            l0 = l1 = l2 = l3 = -3e38f;
        }
        // chunk edge_attr sum (for self-loop mean)
        float es = valid ? eav : 0.f;
#pragma unroll
        for (int mm = 1; mm < 64; mm <<= 1) es += __shfl_xor(es, mm);
        easum += es;
        // per-head chunk max
        float c0 = l0, c1 = l1, c2 = l2, c3 = l3;
#pragma unroll
        for (int mm = 1; mm < 64; mm <<= 1) {
            c0 = fmaxf(c0, __shfl_xor(c0, mm));
            c1 = fmaxf(c1, __shfl_xor(c1, mm));
            c2 = fmaxf(c2, __shfl_xor(c2, mm));
            c3 = fmaxf(c3, __shfl_xor(c3, mm));
        }
        float n0 = fmaxf(m0, c0), n1 = fmaxf(m1, c1);
        float n2 = fmaxf(m2, c2), n3 = fmaxf(m3, c3);
        // rescale own-head state (lane's channel head)
        float mo = sel4s(m0, m1, m2, m3, hc);
        float mn = sel4s(n0, n1, n2, n3, hc);
        float r = __expf(mo - mn);
        s *= r; acc *= r;
        if (valid) {
            float4 pv4;
            pv4.x = __expf(l0 - n0);
            pv4.y = __expf(l1 - n1);
            pv4.z = __expf(l2 - n2);
            pv4.w = __expf(l3 - n3);
            *(float4*)&ldsP[wslot][lane][0] = pv4;
            ldsS[wslot][lane] = srci;
        }
        m0 = n0; m1 = n1; m2 = n2; m3 = n3;
        asm volatile("s_waitcnt lgkmcnt(0)" ::: "memory");
        __builtin_amdgcn_sched_barrier(0);
        // phase B: lane = channel, accumulate
#pragma unroll 4
        for (int i = 0; i < cc; ++i) {
            float pv = ldsP[wslot][i][hc];
            int si = ldsS[wslot][i];
            float xv = xw[(size_t)si * HC + lane];
            s += pv;
            acc = fmaf(pv, xv, acc);
        }
        asm volatile("s_waitcnt lgkmcnt(0)" ::: "memory");
        __builtin_amdgcn_sched_barrier(0);
    }
    // self-loop (fill_value='mean')
    float4 ss4 = *(const float4*)&a_src[(size_t)n * 4];
    float asn = sel4s(ss4.x, ss4.y, ss4.z, ss4.w, hc);
    float adn = sel4s(ad4.x, ad4.y, ad4.z, ad4.w, hc);
    float cen = sel4s(ce4.x, ce4.y, ce4.z, ce4.w, hc);
    float mown = sel4s(m0, m1, m2, m3, hc);
    float eavm = easum / fmaxf((float)cnt, 1.f);
    float al = lrelu(asn + adn + eavm * cen);
    float mn = fmaxf(mown, al);
    float r = __expf(mown - mn);
    float p = __expf(al - mn);
    float xself = xw[(size_t)n * HC + lane];
    s = s * r + p;
    acc = acc * r + p * xself;
    out[(size_t)n * HC + lane] = fmaxf(acc / s + bias[lane], 0.f);
}

extern "C" void kernel_launch(void* const* d_in, const int* in_sizes, int n_in,
                              void* d_out, int out_size, void* d_ws, size_t ws_size,
                              hipStream_t stream) {
    const float* x        = (const float*)d_in[0];
    const int*   ei       = (const int*)d_in[1];
    const float* ea       = (const float*)d_in[2];
    const float* W        = (const float*)d_in[3];
    const float* W_edge   = (const float*)d_in[4];
    const float* att_src  = (const float*)d_in[5];
    const float* att_dst  = (const float*)d_in[6];
    const float* att_edge = (const float*)d_in[7];
    const float* bias     = (const float*)d_in[8];
    float* out = (float*)d_out;

    float* ws = (float*)d_ws;
    float* xw     = ws;                                 // 64N floats
    uint2* esort  = (uint2*)(xw + (size_t)HC * NN);     // E uint2
    float* a_src  = (float*)(esort + NE);               // 4N
    float* a_dst  = a_src + (size_t)HEADS * NN;         // 4N
    int*   deg    = (int*)(a_dst + (size_t)HEADS * NN); // N
    int*   offs   = deg + NN;                           // N
    int*   cursor = offs + NN;                          // N
    int*   bsum   = cursor + NN;                        // 256
    int*   boff   = bsum + 256;                         // 256

    k_zero<<<64, 256, 0, stream>>>(deg, (size_t)NN);
    k_deg<<<(NE + 255) / 256, 256, 0, stream>>>(ei, deg);
    k_xw<<<(NN + 63) / 64, 256, 0, stream>>>(x, W, att_src, att_dst, xw, a_src, a_dst);
    k_scan1<<<SCAN_NB, 256, 0, stream>>>(deg, offs, bsum);
    k_scan2<<<1, 256, 0, stream>>>(bsum, boff);
    k_scan3<<<SCAN_NB, 256, 0, stream>>>(boff, offs, cursor);
    k_fill<<<(NE + 255) / 256, 256, 0, stream>>>(ei, ea, cursor, esort);
    k_gather<<<NN / 4, 256, 0, stream>>>(
        esort, offs, deg, a_src, a_dst, xw, W_edge, att_edge, bias, out);
}

// Round 5
// 197.389 us; speedup vs baseline: 3.6084x; 1.1964x over previous
//
#include <hip/hip_runtime.h>
#include <math.h>

#define NN 50000
#define NE 800000
#define INF_ 128
#define HEADS 4
#define OUTF 16
#define HC 64
#define NEG_SLOPE 0.2f
#define NBKT 196            // ceil(NN/256) coarse buckets (256 dsts each)
#define CHA 4096            // edges per k_binA block
#define NBA ((NE + CHA - 1) / CHA)
#define WPB 4               // waves per block in gather

// ---------- K2: xw = x @ W + per-node logits ----------
__global__ __launch_bounds__(256) void k_xw(
    const float* __restrict__ x, const float* __restrict__ W,
    const float* __restrict__ att_src, const float* __restrict__ att_dst,
    float* __restrict__ xw, float* __restrict__ a_src, float* __restrict__ a_dst) {
    __shared__ float sW[INF_ * HC];       // 32 KB, k-major [128][64]
    __shared__ float sx[64 * 132];        // padded rows
    int t = threadIdx.x;
    int n0 = blockIdx.x * 64;
    for (int i = t; i < (INF_ * HC) / 4; i += 256)
        ((float4*)sW)[i] = ((const float4*)W)[i];
    for (int i = t; i < 64 * 32; i += 256) {
        int r = i >> 5, k4 = (i & 31) * 4;
        int n = n0 + r;
        float4 v = (n < NN) ? *(const float4*)&x[(size_t)n * INF_ + k4]
                            : make_float4(0.f, 0.f, 0.f, 0.f);
        *(float4*)&sx[r * 132 + k4] = v;
    }
    __syncthreads();
    int cg = t & 15;
    int q  = t >> 4;
    int c0 = cg * 4;
    float acc[4][4];
#pragma unroll
    for (int j = 0; j < 4; ++j)
#pragma unroll
        for (int i = 0; i < 4; ++i) acc[j][i] = 0.f;
#pragma unroll 4
    for (int k = 0; k < INF_; ++k) {
        float4 w = *(const float4*)&sW[k * HC + c0];
#pragma unroll
        for (int j = 0; j < 4; ++j) {
            float xv = sx[(q * 4 + j) * 132 + k];
            acc[j][0] = fmaf(xv, w.x, acc[j][0]);
            acc[j][1] = fmaf(xv, w.y, acc[j][1]);
            acc[j][2] = fmaf(xv, w.z, acc[j][2]);
            acc[j][3] = fmaf(xv, w.w, acc[j][3]);
        }
    }
    int h = c0 >> 4;
    int cl = c0 & 15;
    float ps[4], pd[4];
#pragma unroll
    for (int j = 0; j < 4; ++j) {
        float s_ = 0.f, d_ = 0.f;
#pragma unroll
        for (int i = 0; i < 4; ++i) {
            s_ = fmaf(acc[j][i], att_src[h * OUTF + cl + i], s_);
            d_ = fmaf(acc[j][i], att_dst[h * OUTF + cl + i], d_);
        }
        ps[j] = s_; pd[j] = d_;
    }
#pragma unroll
    for (int m = 1; m < 4; m <<= 1)
#pragma unroll
        for (int j = 0; j < 4; ++j) {
            ps[j] += __shfl_xor(ps[j], m);
            pd[j] += __shfl_xor(pd[j], m);
        }
#pragma unroll
    for (int j = 0; j < 4; ++j) {
        int n = n0 + q * 4 + j;
        if (n < NN) {
            *(float4*)&xw[(size_t)n * HC + c0] =
                make_float4(acc[j][0], acc[j][1], acc[j][2], acc[j][3]);
            if ((cg & 3) == 0) {
                a_src[n * HEADS + h] = ps[j];
                a_dst[n * HEADS + h] = pd[j];
            }
        }
    }
}

// ---------- coarse histogram (dst >> 8) ----------
__global__ __launch_bounds__(256) void k_coarse(const int* __restrict__ ei,
                                                int* __restrict__ ccnt) {
    __shared__ int lh[NBKT];
    int t = threadIdx.x;
    for (int i = t; i < NBKT; i += 256) lh[i] = 0;
    __syncthreads();
    for (int i = blockIdx.x * 256 + t; i < NE; i += gridDim.x * 256)
        atomicAdd(&lh[ei[NE + i] >> 8], 1);
    __syncthreads();
    for (int i = t; i < NBKT; i += 256)
        if (lh[i]) atomicAdd(&ccnt[i], lh[i]);
}

// ---------- scan bucket counts -> bases + cursors ----------
__global__ void k_scanb(const int* __restrict__ ccnt, int* __restrict__ boff,
                        int* __restrict__ ccur) {
    __shared__ int sd[256];
    int t = threadIdx.x;
    int v = (t < NBKT) ? ccnt[t] : 0;
    sd[t] = v; __syncthreads();
    for (int o = 1; o < 256; o <<= 1) {
        int a = (t >= o) ? sd[t - o] : 0;
        __syncthreads();
        sd[t] += a;
        __syncthreads();
    }
    int ex = sd[t] - v;
    if (t < NBKT) { boff[t] = ex; ccur[t] = ex; }
    if (t == NBKT - 1) boff[NBKT] = sd[t];
}

// ---------- pass A: bin edges into coarse buckets (block-private runs) ----------
__global__ __launch_bounds__(256) void k_binA(const int* __restrict__ ei,
                                              const float* __restrict__ ea,
                                              int* __restrict__ ccur,
                                              uint2* __restrict__ ebuf) {
    __shared__ int lh[NBKT], lcur[NBKT];
    int t = threadIdx.x;
    int e0 = blockIdx.x * CHA;
    int ecnt = NE - e0; if (ecnt > CHA) ecnt = CHA;
    for (int i = t; i < NBKT; i += 256) lh[i] = 0;
    __syncthreads();
    for (int i = t; i < ecnt; i += 256)
        atomicAdd(&lh[ei[NE + e0 + i] >> 8], 1);
    __syncthreads();
    for (int i = t; i < NBKT; i += 256)
        lcur[i] = lh[i] ? atomicAdd(&ccur[i], lh[i]) : 0;
    __syncthreads();
    for (int i = t; i < ecnt; i += 256) {
        int e = e0 + i;
        int dst = ei[NE + e];
        int b = dst >> 8;
        int p = atomicAdd(&lcur[b], 1);
        uint2 pk;
        pk.x = (unsigned)ei[e] | ((unsigned)(dst & 255) << 16);   // src<65536
        pk.y = __float_as_uint(ea[e]);
        ebuf[p] = pk;
    }
}

// ---------- pass B: exact per-dst sort within each coarse bucket ----------
__global__ __launch_bounds__(256) void k_binB(const int* __restrict__ boff,
                                              const uint2* __restrict__ ebuf,
                                              uint2* __restrict__ esort,
                                              int* __restrict__ deg,
                                              int* __restrict__ offs) {
    __shared__ int lh[256], lo_[256], lcur[256], sd[256];
    int t = threadIdx.x;
    int b = blockIdx.x;
    int base = boff[b];
    int cnt = boff[b + 1] - base;
    lh[t] = 0;
    __syncthreads();
    for (int i = t; i < cnt; i += 256)
        atomicAdd(&lh[(ebuf[base + i].x >> 16) & 255], 1);
    __syncthreads();
    int v = lh[t];
    sd[t] = v; __syncthreads();
    for (int o = 1; o < 256; o <<= 1) {
        int a = (t >= o) ? sd[t - o] : 0;
        __syncthreads();
        sd[t] += a;
        __syncthreads();
    }
    int ex = sd[t] - v;
    lo_[t] = ex; lcur[t] = ex;
    __syncthreads();
    for (int i = t; i < cnt; i += 256) {
        uint2 pk = ebuf[base + i];
        int d = (pk.x >> 16) & 255;
        int p = atomicAdd(&lcur[d], 1);
        esort[base + p] = make_uint2(pk.x & 0xFFFFu, pk.y);
    }
    int n = (b << 8) + t;
    if (n < NN) { deg[n] = v; offs[n] = base + ex; }
}

// ---------- helpers ----------
__device__ __forceinline__ float sel4s(float a, float b, float c, float d, int h) {
    float ab = (h & 1) ? b : a;
    float cd = (h & 1) ? d : c;
    return (h & 2) ? cd : ab;
}
__device__ __forceinline__ float lrelu(float v) {
    return v > 0.f ? v : NEG_SLOPE * v;
}

// ---------- K4: gather, chunked flash-style ----------
__global__ __launch_bounds__(256) void k_gather(
    const uint2* __restrict__ esort, const int* __restrict__ offs,
    const int* __restrict__ deg,
    const float* __restrict__ a_src, const float* __restrict__ a_dst,
    const float* __restrict__ xw,
    const float* __restrict__ W_edge, const float* __restrict__ att_edge,
    const float* __restrict__ bias, float* __restrict__ out) {
    __shared__ __align__(16) float sce[4];
    __shared__ __align__(16) float ldsP[WPB][64][4];
    __shared__ int ldsS[WPB][64];
    int t = threadIdx.x;
    if (t < 4) {
        float s_ = 0.f;
        for (int k = 0; k < OUTF; ++k)
            s_ = fmaf(W_edge[t * OUTF + k], att_edge[t * OUTF + k], s_);
        sce[t] = s_;
    }
    __syncthreads();
    int lane = t & 63;
    int wslot = t >> 6;
    int n = (blockIdx.x << 2) + wslot;
    int hc = lane >> 4;

    float4 ce4 = *(float4*)sce;
    float4 ad4 = *(const float4*)&a_dst[(size_t)n * 4];
    int start = offs[n];
    int cnt = deg[n];

    float m0 = -3e38f, m1 = -3e38f, m2 = -3e38f, m3 = -3e38f;
    float s = 0.f, acc = 0.f, easum = 0.f;

    int nch = (cnt + 63) >> 6;
    for (int ch = 0; ch < nch; ++ch) {
        int base = start + (ch << 6);
        int cc = cnt - (ch << 6); if (cc > 64) cc = 64;
        bool valid = lane < cc;
        float l0, l1, l2, l3, eav = 0.f; int srci = 0;
        if (valid) {
            uint2 pk = esort[base + lane];
            srci = (int)pk.x;
            eav = __uint_as_float(pk.y);
            float4 as4 = *(const float4*)&a_src[(size_t)srci * 4];
            l0 = lrelu(as4.x + ad4.x + eav * ce4.x);
            l1 = lrelu(as4.y + ad4.y + eav * ce4.y);
            l2 = lrelu(as4.z + ad4.z + eav * ce4.z);
            l3 = lrelu(as4.w + ad4.w + eav * ce4.w);
        } else {
            l0 = l1 = l2 = l3 = -3e38f;
        }
        float es = valid ? eav : 0.f;
#pragma unroll
        for (int mm = 1; mm < 64; mm <<= 1) es += __shfl_xor(es, mm);
        easum += es;
        float c0 = l0, c1 = l1, c2 = l2, c3 = l3;
#pragma unroll
        for (int mm = 1; mm < 64; mm <<= 1) {
            c0 = fmaxf(c0, __shfl_xor(c0, mm));
            c1 = fmaxf(c1, __shfl_xor(c1, mm));
            c2 = fmaxf(c2, __shfl_xor(c2, mm));
            c3 = fmaxf(c3, __shfl_xor(c3, mm));
        }
        float n0 = fmaxf(m0, c0), n1 = fmaxf(m1, c1);
        float n2 = fmaxf(m2, c2), n3 = fmaxf(m3, c3);
        float mo = sel4s(m0, m1, m2, m3, hc);
        float mn = sel4s(n0, n1, n2, n3, hc);
        float r = __expf(mo - mn);
        s *= r; acc *= r;
        if (valid) {
            float4 pv4;
            pv4.x = __expf(l0 - n0);
            pv4.y = __expf(l1 - n1);
            pv4.z = __expf(l2 - n2);
            pv4.w = __expf(l3 - n3);
            *(float4*)&ldsP[wslot][lane][0] = pv4;
            ldsS[wslot][lane] = srci;
        }
        m0 = n0; m1 = n1; m2 = n2; m3 = n3;
        asm volatile("s_waitcnt lgkmcnt(0)" ::: "memory");
        __builtin_amdgcn_sched_barrier(0);
#pragma unroll 4
        for (int i = 0; i < cc; ++i) {
            float pv = ldsP[wslot][i][hc];
            int si = ldsS[wslot][i];
            float xv = xw[(size_t)si * HC + lane];
            s += pv;
            acc = fmaf(pv, xv, acc);
        }
        asm volatile("s_waitcnt lgkmcnt(0)" ::: "memory");
        __builtin_amdgcn_sched_barrier(0);
    }
    float4 ss4 = *(const float4*)&a_src[(size_t)n * 4];
    float asn = sel4s(ss4.x, ss4.y, ss4.z, ss4.w, hc);
    float adn = sel4s(ad4.x, ad4.y, ad4.z, ad4.w, hc);
    float cen = sel4s(ce4.x, ce4.y, ce4.z, ce4.w, hc);
    float mown = sel4s(m0, m1, m2, m3, hc);
    float eavm = easum / fmaxf((float)cnt, 1.f);
    float al = lrelu(asn + adn + eavm * cen);
    float mn = fmaxf(mown, al);
    float r = __expf(mown - mn);
    float p = __expf(al - mn);
    float xself = xw[(size_t)n * HC + lane];
    s = s * r + p;
    acc = acc * r + p * xself;
    out[(size_t)n * HC + lane] = fmaxf(acc / s + bias[lane], 0.f);
}

extern "C" void kernel_launch(void* const* d_in, const int* in_sizes, int n_in,
                              void* d_out, int out_size, void* d_ws, size_t ws_size,
                              hipStream_t stream) {
    const float* x        = (const float*)d_in[0];
    const int*   ei       = (const int*)d_in[1];
    const float* ea       = (const float*)d_in[2];
    const float* W        = (const float*)d_in[3];
    const float* W_edge   = (const float*)d_in[4];
    const float* att_src  = (const float*)d_in[5];
    const float* att_dst  = (const float*)d_in[6];
    const float* att_edge = (const float*)d_in[7];
    const float* bias     = (const float*)d_in[8];
    float* out = (float*)d_out;

    float* ws = (float*)d_ws;
    float* xw     = ws;                                   // 64N floats
    uint2* esort  = (uint2*)(xw + (size_t)HC * NN);       // E uint2
    uint2* ebuf   = esort + NE;                           // E uint2
    float* a_src  = (float*)(ebuf + NE);                  // 4N
    float* a_dst  = a_src + (size_t)HEADS * NN;           // 4N
    int*   deg    = (int*)(a_dst + (size_t)HEADS * NN);   // N
    int*   offs   = deg + NN;                             // N
    int*   ccnt   = offs + NN;                            // NBKT
    int*   ccur   = ccnt + NBKT;                          // NBKT
    int*   boff   = ccur + NBKT;                          // NBKT+1

    hipMemsetAsync(ccnt, 0, NBKT * sizeof(int), stream);
    k_coarse<<<256, 256, 0, stream>>>(ei, ccnt);
    k_scanb<<<1, 256, 0, stream>>>(ccnt, boff, ccur);
    k_binA<<<NBA, 256, 0, stream>>>(ei, ea, ccur, ebuf);
    k_binB<<<NBKT, 256, 0, stream>>>(boff, ebuf, esort, deg, offs);
    k_xw<<<(NN + 63) / 64, 256, 0, stream>>>(x, W, att_src, att_dst, xw, a_src, a_dst);
    k_gather<<<NN / 4, 256, 0, stream>>>(
        esort, offs, deg, a_src, a_dst, xw, W_edge, att_edge, bias, out);
}

// Round 6
// 191.120 us; speedup vs baseline: 3.7268x; 1.0328x over previous
//
#include <hip/hip_runtime.h>
#include <hip/hip_fp16.h>
#include <math.h>

#define NN 50000
#define NE 800000
#define INF_ 128
#define HEADS 4
#define OUTF 16
#define HC 64
#define NEG_SLOPE 0.2f
#define NBKT 196            // ceil(NN/256) coarse buckets (256 dsts each)
#define CHA 4096            // edges per k_binA block
#define NBA ((NE + CHA - 1) / CHA)
#define WPB 4               // waves per block in gather

__device__ __forceinline__ unsigned short h2u(float f) {
    __half h = __float2half(f);
    return *(unsigned short*)&h;
}
__device__ __forceinline__ float u2f(unsigned short u) {
    __half h = *(__half*)&u;
    return __half2float(h);
}

// ---------- K2: xw = x @ W (fp16 out) + per-node logits ----------
__global__ __launch_bounds__(256) void k_xw(
    const float* __restrict__ x, const float* __restrict__ W,
    const float* __restrict__ att_src, const float* __restrict__ att_dst,
    unsigned short* __restrict__ xw16, unsigned short* __restrict__ a_src16,
    float* __restrict__ a_dst) {
    __shared__ float sW[INF_ * HC];       // 32 KB, k-major [128][64]
    __shared__ float sx[64 * 132];        // padded rows
    int t = threadIdx.x;
    int n0 = blockIdx.x * 64;
    for (int i = t; i < (INF_ * HC) / 4; i += 256)
        ((float4*)sW)[i] = ((const float4*)W)[i];
    for (int i = t; i < 64 * 32; i += 256) {
        int r = i >> 5, k4 = (i & 31) * 4;
        int n = n0 + r;
        float4 v = (n < NN) ? *(const float4*)&x[(size_t)n * INF_ + k4]
                            : make_float4(0.f, 0.f, 0.f, 0.f);
        *(float4*)&sx[r * 132 + k4] = v;
    }
    __syncthreads();
    int cg = t & 15;
    int q  = t >> 4;
    int c0 = cg * 4;
    float acc[4][4];
#pragma unroll
    for (int j = 0; j < 4; ++j)
#pragma unroll
        for (int i = 0; i < 4; ++i) acc[j][i] = 0.f;
#pragma unroll 4
    for (int k = 0; k < INF_; ++k) {
        float4 w = *(const float4*)&sW[k * HC + c0];
#pragma unroll
        for (int j = 0; j < 4; ++j) {
            float xv = sx[(q * 4 + j) * 132 + k];
            acc[j][0] = fmaf(xv, w.x, acc[j][0]);
            acc[j][1] = fmaf(xv, w.y, acc[j][1]);
            acc[j][2] = fmaf(xv, w.z, acc[j][2]);
            acc[j][3] = fmaf(xv, w.w, acc[j][3]);
        }
    }
    int h = c0 >> 4;
    int cl = c0 & 15;
    float ps[4], pd[4];
#pragma unroll
    for (int j = 0; j < 4; ++j) {
        float s_ = 0.f, d_ = 0.f;
#pragma unroll
        for (int i = 0; i < 4; ++i) {
            s_ = fmaf(acc[j][i], att_src[h * OUTF + cl + i], s_);
            d_ = fmaf(acc[j][i], att_dst[h * OUTF + cl + i], d_);
        }
        ps[j] = s_; pd[j] = d_;
    }
#pragma unroll
    for (int m = 1; m < 4; m <<= 1)
#pragma unroll
        for (int j = 0; j < 4; ++j) {
            ps[j] += __shfl_xor(ps[j], m);
            pd[j] += __shfl_xor(pd[j], m);
        }
#pragma unroll
    for (int j = 0; j < 4; ++j) {
        int n = n0 + q * 4 + j;
        if (n < NN) {
            ushort4 u;
            u.x = h2u(acc[j][0]); u.y = h2u(acc[j][1]);
            u.z = h2u(acc[j][2]); u.w = h2u(acc[j][3]);
            *(ushort4*)&xw16[(size_t)n * HC + c0] = u;
            if ((cg & 3) == 0) {
                a_src16[n * HEADS + h] = h2u(ps[j]);
                a_dst[n * HEADS + h] = pd[j];
            }
        }
    }
}

// ---------- coarse histogram (dst >> 8) ----------
__global__ __launch_bounds__(256) void k_coarse(const int* __restrict__ ei,
                                                int* __restrict__ ccnt) {
    __shared__ int lh[NBKT];
    int t = threadIdx.x;
    for (int i = t; i < NBKT; i += 256) lh[i] = 0;
    __syncthreads();
    for (int i = blockIdx.x * 256 + t; i < NE; i += gridDim.x * 256)
        atomicAdd(&lh[ei[NE + i] >> 8], 1);
    __syncthreads();
    for (int i = t; i < NBKT; i += 256)
        if (lh[i]) atomicAdd(&ccnt[i], lh[i]);
}

// ---------- scan bucket counts -> bases + cursors ----------
__global__ void k_scanb(const int* __restrict__ ccnt, int* __restrict__ boff,
                        int* __restrict__ ccur) {
    __shared__ int sd[256];
    int t = threadIdx.x;
    int v = (t < NBKT) ? ccnt[t] : 0;
    sd[t] = v; __syncthreads();
    for (int o = 1; o < 256; o <<= 1) {
        int a = (t >= o) ? sd[t - o] : 0;
        __syncthreads();
        sd[t] += a;
        __syncthreads();
    }
    int ex = sd[t] - v;
    if (t < NBKT) { boff[t] = ex; ccur[t] = ex; }
    if (t == NBKT - 1) boff[NBKT] = sd[t];
}

// ---------- pass A: bin edges into coarse buckets (block-private runs) ----------
__global__ __launch_bounds__(256) void k_binA(const int* __restrict__ ei,
                                              const float* __restrict__ ea,
                                              int* __restrict__ ccur,
                                              uint2* __restrict__ ebuf) {
    __shared__ int lh[NBKT], lcur[NBKT];
    int t = threadIdx.x;
    int e0 = blockIdx.x * CHA;
    int ecnt = NE - e0; if (ecnt > CHA) ecnt = CHA;
    for (int i = t; i < NBKT; i += 256) lh[i] = 0;
    __syncthreads();
    for (int i = t; i < ecnt; i += 256)
        atomicAdd(&lh[ei[NE + e0 + i] >> 8], 1);
    __syncthreads();
    for (int i = t; i < NBKT; i += 256)
        lcur[i] = lh[i] ? atomicAdd(&ccur[i], lh[i]) : 0;
    __syncthreads();
    for (int i = t; i < ecnt; i += 256) {
        int e = e0 + i;
        int dst = ei[NE + e];
        int b = dst >> 8;
        int p = atomicAdd(&lcur[b], 1);
        uint2 pk;
        pk.x = (unsigned)ei[e] | ((unsigned)(dst & 255) << 16);   // src<65536
        pk.y = __float_as_uint(ea[e]);
        ebuf[p] = pk;
    }
}

// ---------- pass B: exact per-dst sort within each coarse bucket ----------
__global__ __launch_bounds__(256) void k_binB(const int* __restrict__ boff,
                                              const uint2* __restrict__ ebuf,
                                              uint2* __restrict__ esort,
                                              int* __restrict__ deg,
                                              int* __restrict__ offs) {
    __shared__ int lh[256], lo_[256], lcur[256], sd[256];
    int t = threadIdx.x;
    int b = blockIdx.x;
    int base = boff[b];
    int cnt = boff[b + 1] - base;
    lh[t] = 0;
    __syncthreads();
    for (int i = t; i < cnt; i += 256)
        atomicAdd(&lh[(ebuf[base + i].x >> 16) & 255], 1);
    __syncthreads();
    int v = lh[t];
    sd[t] = v; __syncthreads();
    for (int o = 1; o < 256; o <<= 1) {
        int a = (t >= o) ? sd[t - o] : 0;
        __syncthreads();
        sd[t] += a;
        __syncthreads();
    }
    int ex = sd[t] - v;
    lo_[t] = ex; lcur[t] = ex;
    __syncthreads();
    for (int i = t; i < cnt; i += 256) {
        uint2 pk = ebuf[base + i];
        int d = (pk.x >> 16) & 255;
        int p = atomicAdd(&lcur[d], 1);
        esort[base + p] = make_uint2(pk.x & 0xFFFFu, pk.y);
    }
    int n = (b << 8) + t;
    if (n < NN) { deg[n] = v; offs[n] = base + ex; }
}

// ---------- helpers ----------
__device__ __forceinline__ float sel4s(float a, float b, float c, float d, int h) {
    float ab = (h & 1) ? b : a;
    float cd = (h & 1) ? d : c;
    return (h & 2) ? cd : ab;
}
__device__ __forceinline__ float lrelu(float v) {
    return v > 0.f ? v : NEG_SLOPE * v;
}

// ---------- K4: gather, chunked flash-style, fp16 payloads ----------
__global__ __launch_bounds__(256) void k_gather(
    const uint2* __restrict__ esort, const int* __restrict__ offs,
    const int* __restrict__ deg,
    const unsigned short* __restrict__ a_src16, const float* __restrict__ a_dst,
    const unsigned short* __restrict__ xw16,
    const float* __restrict__ W_edge, const float* __restrict__ att_edge,
    const float* __restrict__ bias, float* __restrict__ out) {
    __shared__ __align__(16) float sce[4];
    __shared__ __align__(16) float ldsP[WPB][64][4];
    __shared__ int ldsS[WPB][64];
    int t = threadIdx.x;
    if (t < 4) {
        float s_ = 0.f;
        for (int k = 0; k < OUTF; ++k)
            s_ = fmaf(W_edge[t * OUTF + k], att_edge[t * OUTF + k], s_);
        sce[t] = s_;
    }
    __syncthreads();
    int lane = t & 63;
    int wslot = t >> 6;
    int n = (blockIdx.x << 2) + wslot;
    int hc = lane >> 4;

    float4 ce4 = *(float4*)sce;
    float4 ad4 = *(const float4*)&a_dst[(size_t)n * 4];
    int start = offs[n];
    int cnt = deg[n];

    float m0 = -3e38f, m1 = -3e38f, m2 = -3e38f, m3 = -3e38f;
    float s = 0.f, acc = 0.f, easum = 0.f;

    int nch = (cnt + 63) >> 6;
    for (int ch = 0; ch < nch; ++ch) {
        int base = start + (ch << 6);
        int cc = cnt - (ch << 6); if (cc > 64) cc = 64;
        bool valid = lane < cc;
        float l0, l1, l2, l3, eav = 0.f; int srci = 0;
        if (valid) {
            uint2 pk = esort[base + lane];
            srci = (int)pk.x;
            eav = __uint_as_float(pk.y);
            uint2 au = *(const uint2*)&a_src16[(size_t)srci * 4];
            float as0 = u2f((unsigned short)(au.x & 0xFFFF));
            float as1 = u2f((unsigned short)(au.x >> 16));
            float as2 = u2f((unsigned short)(au.y & 0xFFFF));
            float as3 = u2f((unsigned short)(au.y >> 16));
            l0 = lrelu(as0 + ad4.x + eav * ce4.x);
            l1 = lrelu(as1 + ad4.y + eav * ce4.y);
            l2 = lrelu(as2 + ad4.z + eav * ce4.z);
            l3 = lrelu(as3 + ad4.w + eav * ce4.w);
        } else {
            l0 = l1 = l2 = l3 = -3e38f;
        }
        float es = valid ? eav : 0.f;
#pragma unroll
        for (int mm = 1; mm < 64; mm <<= 1) es += __shfl_xor(es, mm);
        easum += es;
        float c0 = l0, c1 = l1, c2 = l2, c3 = l3;
#pragma unroll
        for (int mm = 1; mm < 64; mm <<= 1) {
            c0 = fmaxf(c0, __shfl_xor(c0, mm));
            c1 = fmaxf(c1, __shfl_xor(c1, mm));
            c2 = fmaxf(c2, __shfl_xor(c2, mm));
            c3 = fmaxf(c3, __shfl_xor(c3, mm));
        }
        float n0 = fmaxf(m0, c0), n1 = fmaxf(m1, c1);
        float n2 = fmaxf(m2, c2), n3 = fmaxf(m3, c3);
        float mo = sel4s(m0, m1, m2, m3, hc);
        float mn = sel4s(n0, n1, n2, n3, hc);
        float r = __expf(mo - mn);
        s *= r; acc *= r;
        if (valid) {
            float4 pv4;
            pv4.x = __expf(l0 - n0);
            pv4.y = __expf(l1 - n1);
            pv4.z = __expf(l2 - n2);
            pv4.w = __expf(l3 - n3);
            *(float4*)&ldsP[wslot][lane][0] = pv4;
            ldsS[wslot][lane] = srci;
        }
        m0 = n0; m1 = n1; m2 = n2; m3 = n3;
        asm volatile("s_waitcnt lgkmcnt(0)" ::: "memory");
        __builtin_amdgcn_sched_barrier(0);
#pragma unroll 4
        for (int i = 0; i < cc; ++i) {
            float pv = ldsP[wslot][i][hc];
            int si = ldsS[wslot][i];
            float xv = u2f(xw16[(size_t)si * HC + lane]);
            s += pv;
            acc = fmaf(pv, xv, acc);
        }
        asm volatile("s_waitcnt lgkmcnt(0)" ::: "memory");
        __builtin_amdgcn_sched_barrier(0);
    }
    // self-loop (fill_value='mean')
    uint2 au = *(const uint2*)&a_src16[(size_t)n * 4];
    float ss0 = u2f((unsigned short)(au.x & 0xFFFF));
    float ss1 = u2f((unsigned short)(au.x >> 16));
    float ss2 = u2f((unsigned short)(au.y & 0xFFFF));
    float ss3 = u2f((unsigned short)(au.y >> 16));
    float asn = sel4s(ss0, ss1, ss2, ss3, hc);
    float adn = sel4s(ad4.x, ad4.y, ad4.z, ad4.w, hc);
    float cen = sel4s(ce4.x, ce4.y, ce4.z, ce4.w, hc);
    float mown = sel4s(m0, m1, m2, m3, hc);
    float eavm = easum / fmaxf((float)cnt, 1.f);
    float al = lrelu(asn + adn + eavm * cen);
    float mn = fmaxf(mown, al);
    float r = __expf(mown - mn);
    float p = __expf(al - mn);
    float xself = u2f(xw16[(size_t)n * HC + lane]);
    s = s * r + p;
    acc = acc * r + p * xself;
    out[(size_t)n * HC + lane] = fmaxf(acc / s + bias[lane], 0.f);
}

extern "C" void kernel_launch(void* const* d_in, const int* in_sizes, int n_in,
                              void* d_out, int out_size, void* d_ws, size_t ws_size,
                              hipStream_t stream) {
    const float* x        = (const float*)d_in[0];
    const int*   ei       = (const int*)d_in[1];
    const float* ea       = (const float*)d_in[2];
    const float* W        = (const float*)d_in[3];
    const float* W_edge   = (const float*)d_in[4];
    const float* att_src  = (const float*)d_in[5];
    const float* att_dst  = (const float*)d_in[6];
    const float* att_edge = (const float*)d_in[7];
    const float* bias     = (const float*)d_in[8];
    float* out = (float*)d_out;

    float* ws = (float*)d_ws;
    unsigned short* xw16    = (unsigned short*)ws;              // 64N halves (32N f-eq)
    uint2* esort  = (uint2*)(ws + (size_t)32 * NN);             // E uint2
    uint2* ebuf   = esort + NE;                                 // E uint2
    unsigned short* a_src16 = (unsigned short*)(ebuf + NE);     // 4N halves (2N f-eq)
    float* a_dst  = (float*)(a_src16 + (size_t)HEADS * NN);     // 4N floats
    int*   deg    = (int*)(a_dst + (size_t)HEADS * NN);         // N
    int*   offs   = deg + NN;                                   // N
    int*   ccnt   = offs + NN;                                  // NBKT
    int*   ccur   = ccnt + NBKT;                                // NBKT
    int*   boff   = ccur + NBKT;                                // NBKT+1

    hipMemsetAsync(ccnt, 0, NBKT * sizeof(int), stream);
    k_coarse<<<256, 256, 0, stream>>>(ei, ccnt);
    k_scanb<<<1, 256, 0, stream>>>(ccnt, boff, ccur);
    k_binA<<<NBA, 256, 0, stream>>>(ei, ea, ccur, ebuf);
    k_binB<<<NBKT, 256, 0, stream>>>(boff, ebuf, esort, deg, offs);
    k_xw<<<(NN + 63) / 64, 256, 0, stream>>>(x, W, att_src, att_dst, xw16, a_src16, a_dst);
    k_gather<<<NN / 4, 256, 0, stream>>>(
        esort, offs, deg, a_src16, a_dst, xw16, W_edge, att_edge, bias, out);
}

// Round 7
// 184.689 us; speedup vs baseline: 3.8566x; 1.0348x over previous
//
#include <hip/hip_runtime.h>
#include <hip/hip_fp16.h>
#include <math.h>

#define NN 50000
#define NE 800000
#define INF_ 128
#define HEADS 4
#define OUTF 16
#define HC 64
#define NEG_SLOPE 0.2f
#define NBKT 196            // ceil(NN/256) coarse buckets (256 dsts each)
#define CHA 4096            // edges per k_binA block
#define NBA ((NE + CHA - 1) / CHA)
#define WPB 4               // waves per block in gather
#define XPAD 136            // 128 + 8 halves: row stride 272B -> 2-way (free) LDS conflicts

typedef _Float16 half8 __attribute__((ext_vector_type(8)));
typedef float f32x4 __attribute__((ext_vector_type(4)));

__device__ __forceinline__ unsigned short h2u(float f) {
    __half h = __float2half(f);
    return *(unsigned short*)&h;
}
__device__ __forceinline__ float u2f(unsigned short u) {
    __half h = *(__half*)&u;
    return __half2float(h);
}

// ---------- K2: xw = x @ W via MFMA fp16 + per-node logits ----------
// block = 256 thr (4 waves); block tile 64 nodes x 64 cols, K=128.
// wave w: rows [16w,16w+16), 4 col-tiles x 4 K-steps = 16 mfma.
__global__ __launch_bounds__(256) void k_xw(
    const float* __restrict__ x, const float* __restrict__ W,
    const float* __restrict__ att_src, const float* __restrict__ att_dst,
    unsigned short* __restrict__ xw16, unsigned short* __restrict__ a_src16,
    float* __restrict__ a_dst) {
    __shared__ _Float16 sxh[64][XPAD];   // x tile, fp16
    __shared__ _Float16 sWT[64][XPAD];   // W transposed [col][k], fp16
    int t = threadIdx.x;
    int n0 = blockIdx.x * 64;
    // x tile: 64 rows x 128 cols
    for (int i = t; i < 64 * 32; i += 256) {
        int r = i >> 5, c4 = (i & 31) * 4;
        int n = n0 + r;
        float4 v = (n < NN) ? *(const float4*)&x[(size_t)n * INF_ + c4]
                            : make_float4(0.f, 0.f, 0.f, 0.f);
        sxh[r][c4 + 0] = (_Float16)v.x;
        sxh[r][c4 + 1] = (_Float16)v.y;
        sxh[r][c4 + 2] = (_Float16)v.z;
        sxh[r][c4 + 3] = (_Float16)v.w;
    }
    // W: [128][64] row-major -> sWT[c][k]
    for (int i = t; i < INF_ * HC; i += 256) {
        int k = i >> 6, c = i & 63;
        sWT[c][k] = (_Float16)W[i];
    }
    __syncthreads();
    int w = t >> 6, l = t & 63;
    int lr = l & 15, kg = l >> 4;
    f32x4 acc0 = {0.f,0.f,0.f,0.f}, acc1 = acc0, acc2 = acc0, acc3 = acc0;
#pragma unroll
    for (int kk = 0; kk < 4; ++kk) {
        half8 a = *(half8*)&sxh[w * 16 + lr][kk * 32 + kg * 8];
        half8 b0 = *(half8*)&sWT[0 * 16 + lr][kk * 32 + kg * 8];
        half8 b1 = *(half8*)&sWT[1 * 16 + lr][kk * 32 + kg * 8];
        half8 b2 = *(half8*)&sWT[2 * 16 + lr][kk * 32 + kg * 8];
        half8 b3 = *(half8*)&sWT[3 * 16 + lr][kk * 32 + kg * 8];
        acc0 = __builtin_amdgcn_mfma_f32_16x16x32_f16(a, b0, acc0, 0, 0, 0);
        acc1 = __builtin_amdgcn_mfma_f32_16x16x32_f16(a, b1, acc1, 0, 0, 0);
        acc2 = __builtin_amdgcn_mfma_f32_16x16x32_f16(a, b2, acc2, 0, 0, 0);
        acc3 = __builtin_amdgcn_mfma_f32_16x16x32_f16(a, b3, acc3, 0, 0, 0);
    }
    // C layout: col = ct*16 + (l&15), row(node) = n0 + 16w + (l>>4)*4 + j
    float attS[4], attD[4];
#pragma unroll
    for (int ct = 0; ct < 4; ++ct) {
        attS[ct] = att_src[ct * 16 + lr];
        attD[ct] = att_dst[ct * 16 + lr];
    }
    int rbase = n0 + w * 16 + kg * 4;
    f32x4 accs[4] = {acc0, acc1, acc2, acc3};
#pragma unroll
    for (int ct = 0; ct < 4; ++ct) {
#pragma unroll
        for (int j = 0; j < 4; ++j) {
            float c = accs[ct][j];
            int node = rbase + j;
            if (node < NN)
                xw16[(size_t)node * HC + ct * 16 + lr] = h2u(c);
            float vs = c * attS[ct];
            float vd = c * attD[ct];
#pragma unroll
            for (int m = 1; m < 16; m <<= 1) {
                vs += __shfl_xor(vs, m);
                vd += __shfl_xor(vd, m);
            }
            if (lr == 0 && node < NN) {
                a_src16[node * HEADS + ct] = h2u(vs);
                a_dst[node * HEADS + ct] = vd;
            }
        }
    }
}

// ---------- coarse histogram (dst >> 8) ----------
__global__ __launch_bounds__(256) void k_coarse(const int* __restrict__ ei,
                                                int* __restrict__ ccnt) {
    __shared__ int lh[NBKT];
    int t = threadIdx.x;
    for (int i = t; i < NBKT; i += 256) lh[i] = 0;
    __syncthreads();
    for (int i = blockIdx.x * 256 + t; i < NE; i += gridDim.x * 256)
        atomicAdd(&lh[ei[NE + i] >> 8], 1);
    __syncthreads();
    for (int i = t; i < NBKT; i += 256)
        if (lh[i]) atomicAdd(&ccnt[i], lh[i]);
}

// ---------- scan bucket counts -> bases + cursors ----------
__global__ void k_scanb(const int* __restrict__ ccnt, int* __restrict__ boff,
                        int* __restrict__ ccur) {
    __shared__ int sd[256];
    int t = threadIdx.x;
    int v = (t < NBKT) ? ccnt[t] : 0;
    sd[t] = v; __syncthreads();
    for (int o = 1; o < 256; o <<= 1) {
        int a = (t >= o) ? sd[t - o] : 0;
        __syncthreads();
        sd[t] += a;
        __syncthreads();
    }
    int ex = sd[t] - v;
    if (t < NBKT) { boff[t] = ex; ccur[t] = ex; }
    if (t == NBKT - 1) boff[NBKT] = sd[t];
}

// ---------- pass A: bin edges into coarse buckets (block-private runs) ----------
__global__ __launch_bounds__(256) void k_binA(const int* __restrict__ ei,
                                              const float* __restrict__ ea,
                                              int* __restrict__ ccur,
                                              uint2* __restrict__ ebuf) {
    __shared__ int lh[NBKT], lcur[NBKT];
    int t = threadIdx.x;
    int e0 = blockIdx.x * CHA;
    int ecnt = NE - e0; if (ecnt > CHA) ecnt = CHA;
    for (int i = t; i < NBKT; i += 256) lh[i] = 0;
    __syncthreads();
    for (int i = t; i < ecnt; i += 256)
        atomicAdd(&lh[ei[NE + e0 + i] >> 8], 1);
    __syncthreads();
    for (int i = t; i < NBKT; i += 256)
        lcur[i] = lh[i] ? atomicAdd(&ccur[i], lh[i]) : 0;
    __syncthreads();
    for (int i = t; i < ecnt; i += 256) {
        int e = e0 + i;
        int dst = ei[NE + e];
        int b = dst >> 8;
        int p = atomicAdd(&lcur[b], 1);
        uint2 pk;
        pk.x = (unsigned)ei[e] | ((unsigned)(dst & 255) << 16);   // src<65536
        pk.y = __float_as_uint(ea[e]);
        ebuf[p] = pk;
    }
}

// ---------- pass B: exact per-dst sort within each coarse bucket ----------
__global__ __launch_bounds__(256) void k_binB(const int* __restrict__ boff,
                                              const uint2* __restrict__ ebuf,
                                              uint2* __restrict__ esort,
                                              int* __restrict__ deg,
                                              int* __restrict__ offs) {
    __shared__ int lh[256], lcur[256], sd[256];
    int t = threadIdx.x;
    int b = blockIdx.x;
    int base = boff[b];
    int cnt = boff[b + 1] - base;
    lh[t] = 0;
    __syncthreads();
    for (int i = t; i < cnt; i += 256)
        atomicAdd(&lh[(ebuf[base + i].x >> 16) & 255], 1);
    __syncthreads();
    int v = lh[t];
    sd[t] = v; __syncthreads();
    for (int o = 1; o < 256; o <<= 1) {
        int a = (t >= o) ? sd[t - o] : 0;
        __syncthreads();
        sd[t] += a;
        __syncthreads();
    }
    int ex = sd[t] - v;
    lcur[t] = ex;
    __syncthreads();
    for (int i = t; i < cnt; i += 256) {
        uint2 pk = ebuf[base + i];
        int d = (pk.x >> 16) & 255;
        int p = atomicAdd(&lcur[d], 1);
        esort[base + p] = make_uint2(pk.x & 0xFFFFu, pk.y);
    }
    int n = (b << 8) + t;
    if (n < NN) { deg[n] = v; offs[n] = base + ex; }
}

__device__ __forceinline__ float lrelu(float v) {
    return v > 0.f ? v : NEG_SLOPE * v;
}

// ---------- K4: gather — 16-edge chunks, lane = (head, edge) ----------
__global__ __launch_bounds__(256) void k_gather(
    const uint2* __restrict__ esort, const int* __restrict__ offs,
    const int* __restrict__ deg,
    const unsigned short* __restrict__ a_src16, const float* __restrict__ a_dst,
    const unsigned short* __restrict__ xw16,
    const float* __restrict__ W_edge, const float* __restrict__ att_edge,
    const float* __restrict__ bias, float* __restrict__ out) {
    __shared__ __align__(16) float sce[4];
    __shared__ __align__(16) float ldsP[WPB][16][4];
    __shared__ int ldsS[WPB][16];
    int t = threadIdx.x;
    if (t < 4) {
        float s_ = 0.f;
        for (int k = 0; k < OUTF; ++k)
            s_ = fmaf(W_edge[t * OUTF + k], att_edge[t * OUTF + k], s_);
        sce[t] = s_;
    }
    __syncthreads();
    int lane = t & 63;
    int wslot = t >> 6;
    int n = (blockIdx.x << 2) + wslot;   // grid = NN/4 blocks exactly
    int e16 = lane & 15;                 // edge index within chunk
    int h = lane >> 4;                   // head (phase A) == channel head (phase B)

    float ceh = sce[h];
    float adh = a_dst[n * HEADS + h];
    int start = offs[n];
    int cnt = deg[n];

    float m = -3e38f, s = 0.f, acc = 0.f, easum = 0.f;

    int nch = (cnt + 15) >> 4;
    for (int ch = 0; ch < nch; ++ch) {
        int base = start + (ch << 4);
        int cc = cnt - (ch << 4); if (cc > 16) cc = 16;
        bool valid = e16 < cc;
        uint2 pk = esort[base + e16];          // may overread into ebuf; masked below
        int srci = (int)(pk.x & 0xFFFFu);
        float eav = valid ? __uint_as_float(pk.y) : 0.f;
        float lg = -3e38f;
        {
            float asv = u2f(a_src16[srci * HEADS + h]);
            float v = asv + adh + eav * ceh;
            if (valid) lg = lrelu(v);
        }
        // chunk edge_attr sum (identical in every 16-lane group)
        float es = eav;
#pragma unroll
        for (int mm = 1; mm < 16; mm <<= 1) es += __shfl_xor(es, mm);
        easum += es;
        // per-head chunk max over the 16-lane group
        float cm = lg;
#pragma unroll
        for (int mm = 1; mm < 16; mm <<= 1) cm = fmaxf(cm, __shfl_xor(cm, mm));
        float nh = fmaxf(m, cm);
        float r = __expf(m - nh);
        s *= r; acc *= r;
        m = nh;
        float p = __expf(lg - nh);             // invalid lanes -> 0
        ldsP[wslot][e16][h] = p;
        if (h == 0) ldsS[wslot][e16] = srci;
        asm volatile("s_waitcnt lgkmcnt(0)" ::: "memory");
        __builtin_amdgcn_sched_barrier(0);
        // phase B: lane = channel (head h, sub-channel), accumulate
#pragma unroll 4
        for (int i = 0; i < cc; ++i) {
            float pv = ldsP[wslot][i][h];
            int si = ldsS[wslot][i];
            float xv = u2f(xw16[(size_t)si * HC + lane]);
            s += pv;
            acc = fmaf(pv, xv, acc);
        }
        asm volatile("s_waitcnt lgkmcnt(0)" ::: "memory");
        __builtin_amdgcn_sched_barrier(0);
    }
    // self-loop (fill_value='mean')
    float asn = u2f(a_src16[n * HEADS + h]);
    float eavm = easum / fmaxf((float)cnt, 1.f);
    float al = lrelu(asn + adh + eavm * ceh);
    float mn = fmaxf(m, al);
    float r = __expf(m - mn);
    float p = __expf(al - mn);
    float xself = u2f(xw16[(size_t)n * HC + lane]);
    s = s * r + p;
    acc = acc * r + p * xself;
    out[(size_t)n * HC + lane] = fmaxf(acc / s + bias[lane], 0.f);
}

extern "C" void kernel_launch(void* const* d_in, const int* in_sizes, int n_in,
                              void* d_out, int out_size, void* d_ws, size_t ws_size,
                              hipStream_t stream) {
    const float* x        = (const float*)d_in[0];
    const int*   ei       = (const int*)d_in[1];
    const float* ea       = (const float*)d_in[2];
    const float* W        = (const float*)d_in[3];
    const float* W_edge   = (const float*)d_in[4];
    const float* att_src  = (const float*)d_in[5];
    const float* att_dst  = (const float*)d_in[6];
    const float* att_edge = (const float*)d_in[7];
    const float* bias     = (const float*)d_in[8];
    float* out = (float*)d_out;

    float* ws = (float*)d_ws;
    unsigned short* xw16    = (unsigned short*)ws;              // 64N halves
    uint2* esort  = (uint2*)(ws + (size_t)32 * NN);             // E uint2
    uint2* ebuf   = esort + NE;                                 // E uint2
    unsigned short* a_src16 = (unsigned short*)(ebuf + NE);     // 4N halves
    float* a_dst  = (float*)(a_src16 + (size_t)HEADS * NN);     // 4N floats
    int*   deg    = (int*)(a_dst + (size_t)HEADS * NN);         // N
    int*   offs   = deg + NN;                                   // N
    int*   ccnt   = offs + NN;                                  // NBKT
    int*   ccur   = ccnt + NBKT;                                // NBKT
    int*   boff   = ccur + NBKT;                                // NBKT+1

    hipMemsetAsync(ccnt, 0, NBKT * sizeof(int), stream);
    k_coarse<<<256, 256, 0, stream>>>(ei, ccnt);
    k_scanb<<<1, 256, 0, stream>>>(ccnt, boff, ccur);
    k_binA<<<NBA, 256, 0, stream>>>(ei, ea, ccur, ebuf);
    k_binB<<<NBKT, 256, 0, stream>>>(boff, ebuf, esort, deg, offs);
    k_xw<<<(NN + 63) / 64, 256, 0, stream>>>(x, W, att_src, att_dst, xw16, a_src16, a_dst);
    k_gather<<<NN / 4, 256, 0, stream>>>(
        esort, offs, deg, a_src16, a_dst, xw16, W_edge, att_edge, bias, out);
}